// Round 1
// baseline (24544.847 us; speedup 1.0000x reference)
//
#include <hip/hip_runtime.h>
#include <math.h>

// ---- Problem constants ----
constexpr int BATCH  = 256;
constexpr int SEQ    = 77;
constexpr int DMODEL = 512;
constexpr int NHEAD  = 8;
constexpr int DHEAD  = 64;   // DMODEL / NHEAD
constexpr int DFF    = 2048;
constexpr int NLAYER = 12;
constexpr int NTOK   = BATCH * SEQ;  // 19712 = 154 * 128
constexpr float NEGBIG = -3.402823466e38f; // finfo(f32).min

// ======================================================================
// Embedding: x[n,d] = tok_emb[ids[n], d] + pos_emb[n % SEQ, d]
// ======================================================================
__global__ __launch_bounds__(256) void embed_kernel(
    const int* __restrict__ ids, const float* __restrict__ tok,
    const float* __restrict__ pos, float* __restrict__ x)
{
    int f = blockIdx.x * 256 + threadIdx.x;           // float4 index
    int total = NTOK * (DMODEL / 4);
    if (f >= total) return;
    int n  = f >> 7;            // / 128
    int d4 = f & 127;
    int s  = n % SEQ;
    int id = ids[n];
    float4 t = *(const float4*)&tok[(size_t)id * DMODEL + d4 * 4];
    float4 p = *(const float4*)&pos[(size_t)s  * DMODEL + d4 * 4];
    float4 o; o.x = t.x + p.x; o.y = t.y + p.y; o.z = t.z + p.z; o.w = t.w + p.w;
    *(float4*)&x[(size_t)n * DMODEL + d4 * 4] = o;
}

// ======================================================================
// LayerNorm: one wave (64 lanes) per row of 512.
// ======================================================================
__global__ __launch_bounds__(256) void ln_kernel(
    const float* __restrict__ x, const float* __restrict__ w,
    const float* __restrict__ b, float* __restrict__ out, int nrows)
{
    int row = blockIdx.x * 4 + (threadIdx.x >> 6);
    if (row >= nrows) return;
    int ln = threadIdx.x & 63;
    const float* xr = x + (size_t)row * DMODEL + ln * 8;
    float4 v0 = *(const float4*)xr;
    float4 v1 = *(const float4*)(xr + 4);
    float va[8] = {v0.x, v0.y, v0.z, v0.w, v1.x, v1.y, v1.z, v1.w};
    float sum = 0.f, sq = 0.f;
#pragma unroll
    for (int j = 0; j < 8; ++j) { sum += va[j]; sq = fmaf(va[j], va[j], sq); }
#pragma unroll
    for (int o = 32; o; o >>= 1) { sum += __shfl_xor(sum, o); sq += __shfl_xor(sq, o); }
    float mu  = sum * (1.0f / DMODEL);
    float var = sq * (1.0f / DMODEL) - mu * mu;
    var = fmaxf(var, 0.0f);
    float inv = 1.0f / sqrtf(var + 1e-5f);
    const float* wp = w + ln * 8;
    const float* bp = b + ln * 8;
    float o8[8];
#pragma unroll
    for (int j = 0; j < 8; ++j) o8[j] = (va[j] - mu) * inv * wp[j] + bp[j];
    float* op = out + (size_t)row * DMODEL + ln * 8;
    *(float4*)op       = make_float4(o8[0], o8[1], o8[2], o8[3]);
    *(float4*)(op + 4) = make_float4(o8[4], o8[5], o8[6], o8[7]);
}

// ======================================================================
// Tiled fp32 GEMM: C[M,Nout] = A[M,K] * W[Nout,K]^T  (+bias, fused epilogue)
// mode 0: +bias ; 1: (+bias)*scale ; 2: quickGELU(+bias) ; 3: +bias + R
// BM=BN=128, BK=16, 256 threads, 8x8 per thread (two 4-wide sub-tiles).
// ======================================================================
__global__ __launch_bounds__(256) void gemm_kernel(
    const float* __restrict__ A, const float* __restrict__ W,
    const float* __restrict__ bias, const float* __restrict__ R,
    float* __restrict__ C, int M, int Nout, int K, int mode, float scale)
{
    __shared__ __align__(16) float As[16][132];
    __shared__ __align__(16) float Ws[16][132];
    const int tid = threadIdx.x;
    const int m0 = blockIdx.y * 128;
    const int n0 = blockIdx.x * 128;
    const int tm = tid >> 4;        // 0..15
    const int tn = tid & 15;        // 0..15
    const int lrow = tid >> 2;      // 0..63
    const int lk4  = (tid & 3) * 4; // 0,4,8,12

    float acc[8][8];
#pragma unroll
    for (int i = 0; i < 8; ++i)
#pragma unroll
        for (int j = 0; j < 8; ++j) acc[i][j] = 0.f;

    const float* Ap = A + (size_t)(m0 + lrow) * K + lk4;
    const float* Wp = W + (size_t)(n0 + lrow) * K + lk4;
    const size_t rstride = (size_t)64 * K;

    for (int k0 = 0; k0 < K; k0 += 16) {
        float4 a0 = *(const float4*)(Ap + k0);
        float4 a1 = *(const float4*)(Ap + rstride + k0);
        float4 w0 = *(const float4*)(Wp + k0);
        float4 w1 = *(const float4*)(Wp + rstride + k0);
        __syncthreads();
        As[lk4 + 0][lrow] = a0.x; As[lk4 + 1][lrow] = a0.y;
        As[lk4 + 2][lrow] = a0.z; As[lk4 + 3][lrow] = a0.w;
        As[lk4 + 0][64 + lrow] = a1.x; As[lk4 + 1][64 + lrow] = a1.y;
        As[lk4 + 2][64 + lrow] = a1.z; As[lk4 + 3][64 + lrow] = a1.w;
        Ws[lk4 + 0][lrow] = w0.x; Ws[lk4 + 1][lrow] = w0.y;
        Ws[lk4 + 2][lrow] = w0.z; Ws[lk4 + 3][lrow] = w0.w;
        Ws[lk4 + 0][64 + lrow] = w1.x; Ws[lk4 + 1][64 + lrow] = w1.y;
        Ws[lk4 + 2][64 + lrow] = w1.z; Ws[lk4 + 3][64 + lrow] = w1.w;
        __syncthreads();
#pragma unroll
        for (int kk = 0; kk < 16; ++kk) {
            float4 a0v = *(const float4*)&As[kk][tm * 4];
            float4 a1v = *(const float4*)&As[kk][64 + tm * 4];
            float4 b0v = *(const float4*)&Ws[kk][tn * 4];
            float4 b1v = *(const float4*)&Ws[kk][64 + tn * 4];
            float av[8] = {a0v.x, a0v.y, a0v.z, a0v.w, a1v.x, a1v.y, a1v.z, a1v.w};
            float bv[8] = {b0v.x, b0v.y, b0v.z, b0v.w, b1v.x, b1v.y, b1v.z, b1v.w};
#pragma unroll
            for (int i = 0; i < 8; ++i)
#pragma unroll
                for (int j = 0; j < 8; ++j)
                    acc[i][j] = fmaf(av[i], bv[j], acc[i][j]);
        }
    }

    // epilogue
    float bb0[4], bb1[4];
    const float* biasp = bias + n0;
#pragma unroll
    for (int j = 0; j < 4; ++j) {
        bb0[j] = biasp[tn * 4 + j];
        bb1[j] = biasp[64 + tn * 4 + j];
    }
#pragma unroll
    for (int i = 0; i < 8; ++i) {
        int gm = m0 + ((i < 4) ? (tm * 4 + i) : (64 + tm * 4 + (i - 4)));
        size_t base = (size_t)gm * Nout + n0;
        float o[8];
#pragma unroll
        for (int j = 0; j < 4; ++j) {
            o[j]     = acc[i][j]     + bb0[j];
            o[4 + j] = acc[i][4 + j] + bb1[j];
        }
        if (mode == 1) {
#pragma unroll
            for (int j = 0; j < 8; ++j) o[j] *= scale;
        } else if (mode == 2) {
#pragma unroll
            for (int j = 0; j < 8; ++j) o[j] = o[j] / (1.0f + expf(-1.702f * o[j]));
        } else if (mode == 3) {
            const float* Rp = R + base;
#pragma unroll
            for (int j = 0; j < 4; ++j) {
                o[j]     += Rp[tn * 4 + j];
                o[4 + j] += Rp[64 + tn * 4 + j];
            }
        }
        *(float4*)&C[base + tn * 4]      = make_float4(o[0], o[1], o[2], o[3]);
        *(float4*)&C[base + 64 + tn * 4] = make_float4(o[4], o[5], o[6], o[7]);
    }
}

// ======================================================================
// Attention: one block per (b,h). q/k/v staged to LDS, full 77x77 scores,
// row softmax per wave, PV, write back into the q buffer (safe: each block
// reads exactly the region it writes, reads complete before writes).
// ======================================================================
__global__ __launch_bounds__(256) void attn_kernel(
    const float* __restrict__ q, const float* __restrict__ k,
    const float* __restrict__ v, const int* __restrict__ amask,
    float* __restrict__ out)
{
    const int bh = blockIdx.x;
    const int b = bh / NHEAD;
    const int h = bh % NHEAD;
    __shared__ float qs[SEQ][DHEAD];
    __shared__ float ks[SEQ][DHEAD + 1];   // pad: conflict-free column reads
    __shared__ float vs[SEQ][DHEAD];
    __shared__ float ss[SEQ][SEQ + 3];     // 77x80
    __shared__ float padm[SEQ];
    const int tid = threadIdx.x;

    // stage q,k,v (float4 granularity)
    for (int f = tid; f < SEQ * (DHEAD / 4); f += 256) {
        int s  = f >> 4;          // /16
        int d4 = (f & 15) * 4;
        size_t g = ((size_t)(b * SEQ + s) * DMODEL) + h * DHEAD + d4;
        float4 qv = *(const float4*)&q[g];
        float4 kv = *(const float4*)&k[g];
        float4 vv = *(const float4*)&v[g];
        qs[s][d4] = qv.x; qs[s][d4+1] = qv.y; qs[s][d4+2] = qv.z; qs[s][d4+3] = qv.w;
        ks[s][d4] = kv.x; ks[s][d4+1] = kv.y; ks[s][d4+2] = kv.z; ks[s][d4+3] = kv.w;
        vs[s][d4] = vv.x; vs[s][d4+1] = vv.y; vs[s][d4+2] = vv.z; vs[s][d4+3] = vv.w;
    }
    for (int s = tid; s < SEQ; s += 256)
        padm[s] = (1.0f - (float)amask[b * SEQ + s]) * NEGBIG;
    __syncthreads();

    // scores + mask
    for (int idx = tid; idx < SEQ * SEQ; idx += 256) {
        int qi = idx / SEQ, ki = idx % SEQ;
        float acc = 0.f;
#pragma unroll 8
        for (int d = 0; d < DHEAD; ++d) acc = fmaf(qs[qi][d], ks[ki][d], acc);
        float m = (ki > qi) ? NEGBIG : 0.0f;
        ss[qi][ki] = acc + m + padm[ki];
    }
    __syncthreads();

    // softmax per row: wave w handles rows w, w+4, ...
    const int wv = tid >> 6;
    const int ln = tid & 63;
    for (int qi = wv; qi < SEQ; qi += 4) {
        float s0 = ss[qi][ln];
        float s1 = (ln + 64 < SEQ) ? ss[qi][ln + 64] : -INFINITY;
        float m = fmaxf(s0, s1);
#pragma unroll
        for (int o = 32; o; o >>= 1) m = fmaxf(m, __shfl_xor(m, o));
        float e0 = expf(s0 - m);
        float e1 = (ln + 64 < SEQ) ? expf(s1 - m) : 0.0f;
        float t = e0 + e1;
#pragma unroll
        for (int o = 32; o; o >>= 1) t += __shfl_xor(t, o);
        float r = 1.0f / t;
        ss[qi][ln] = e0 * r;
        if (ln + 64 < SEQ) ss[qi][ln + 64] = e1 * r;
    }
    __syncthreads();

    // PV and writeback
    for (int idx = tid; idx < SEQ * DHEAD; idx += 256) {
        int qi = idx >> 6;       // /64
        int d  = idx & 63;
        float acc = 0.f;
        for (int ki = 0; ki < SEQ; ++ki) acc = fmaf(ss[qi][ki], vs[ki][d], acc);
        out[((size_t)(b * SEQ + qi) * DMODEL) + h * DHEAD + d] = acc;
    }
}

// ======================================================================
// Pooled: per-batch argmax(ids) (first max), copy that row of last_hidden.
// ======================================================================
__global__ __launch_bounds__(64) void pool_kernel(
    const int* __restrict__ ids, const float* __restrict__ lh,
    float* __restrict__ pooled)
{
    int b = blockIdx.x;
    int ln = threadIdx.x;
    __shared__ int sidx;
    if (ln == 0) {
        int best = ids[b * SEQ]; int bi = 0;
        for (int s = 1; s < SEQ; ++s) {
            int vv = ids[b * SEQ + s];
            if (vv > best) { best = vv; bi = s; }
        }
        sidx = bi;
    }
    __syncthreads();
    const float* src = lh + ((size_t)(b * SEQ + sidx)) * DMODEL + ln * 8;
    float* dst = pooled + (size_t)b * DMODEL + ln * 8;
    float4 a = *(const float4*)src;
    float4 c = *(const float4*)(src + 4);
    *(float4*)dst       = a;
    *(float4*)(dst + 4) = c;
}

// ======================================================================
extern "C" void kernel_launch(void* const* d_in, const int* in_sizes, int n_in,
                              void* d_out, int out_size, void* d_ws, size_t ws_size,
                              hipStream_t stream) {
    const int*   ids   = (const int*)d_in[0];
    const int*   amask = (const int*)d_in[1];
    const float* tok   = (const float*)d_in[2];
    const float* pos   = (const float*)d_in[3];
    const float* ln1w  = (const float*)d_in[4];
    const float* ln1b  = (const float*)d_in[5];
    const float* qw    = (const float*)d_in[6];
    const float* qbias = (const float*)d_in[7];
    const float* kw    = (const float*)d_in[8];
    const float* kbias = (const float*)d_in[9];
    const float* vw    = (const float*)d_in[10];
    const float* vbias = (const float*)d_in[11];
    const float* ow    = (const float*)d_in[12];
    const float* obias = (const float*)d_in[13];
    const float* ln2w  = (const float*)d_in[14];
    const float* ln2b  = (const float*)d_in[15];
    const float* f1w   = (const float*)d_in[16];
    const float* f1b   = (const float*)d_in[17];
    const float* f2w   = (const float*)d_in[18];
    const float* f2b   = (const float*)d_in[19];
    const float* lnfw  = (const float*)d_in[20];
    const float* lnfb  = (const float*)d_in[21];

    float* ws = (float*)d_ws;
    const size_t ND = (size_t)NTOK * DMODEL;   // 10,092,544 floats
    float* x    = ws;
    float* hbuf = x + ND;
    float* qb   = hbuf + ND;
    float* kb   = qb + ND;
    float* vb   = kb + ND;
    float* ff   = vb + ND;                      // NTOK * DFF floats
    // total ws need: (5*ND + NTOK*DFF)*4 B ~= 363 MB

    const float scale = 0.125f;                 // HD^-0.5
    dim3 g512(DMODEL / 128, NTOK / 128);        // (4, 154)
    dim3 g2048(DFF / 128, NTOK / 128);          // (16, 154)

    embed_kernel<<<(NTOK * (DMODEL / 4) + 255) / 256, 256, 0, stream>>>(ids, tok, pos, x);

    for (int l = 0; l < NLAYER; ++l) {
        const size_t wD2  = (size_t)l * DMODEL * DMODEL;
        const size_t wDF  = (size_t)l * DFF * DMODEL;
        const size_t oD   = (size_t)l * DMODEL;
        const size_t oF   = (size_t)l * DFF;

        ln_kernel<<<NTOK / 4, 256, 0, stream>>>(x, ln1w + oD, ln1b + oD, hbuf, NTOK);
        gemm_kernel<<<g512, 256, 0, stream>>>(hbuf, qw + wD2, qbias + oD, nullptr, qb,
                                              NTOK, DMODEL, DMODEL, 1, scale);
        gemm_kernel<<<g512, 256, 0, stream>>>(hbuf, kw + wD2, kbias + oD, nullptr, kb,
                                              NTOK, DMODEL, DMODEL, 0, 1.0f);
        gemm_kernel<<<g512, 256, 0, stream>>>(hbuf, vw + wD2, vbias + oD, nullptr, vb,
                                              NTOK, DMODEL, DMODEL, 0, 1.0f);
        attn_kernel<<<BATCH * NHEAD, 256, 0, stream>>>(qb, kb, vb, amask, qb);
        gemm_kernel<<<g512, 256, 0, stream>>>(qb, ow + wD2, obias + oD, x, x,
                                              NTOK, DMODEL, DMODEL, 3, 1.0f);
        ln_kernel<<<NTOK / 4, 256, 0, stream>>>(x, ln2w + oD, ln2b + oD, hbuf, NTOK);
        gemm_kernel<<<g2048, 256, 0, stream>>>(hbuf, f1w + wDF, f1b + oF, nullptr, ff,
                                               NTOK, DFF, DMODEL, 2, 1.0f);
        gemm_kernel<<<g512, 256, 0, stream>>>(ff, f2w + wDF, f2b + oD, x, x,
                                              NTOK, DMODEL, DFF, 3, 1.0f);
    }

    float* outf = (float*)d_out;
    ln_kernel<<<NTOK / 4, 256, 0, stream>>>(x, lnfw, lnfb, outf, NTOK);
    pool_kernel<<<BATCH, 64, 0, stream>>>(ids, outf, outf + ND);
}

// Round 2
// 7633.117 us; speedup vs baseline: 3.2156x; 3.2156x over previous
//
#include <hip/hip_runtime.h>
#include <math.h>

// ---- Problem constants ----
constexpr int BATCH  = 256;
constexpr int SEQ    = 77;
constexpr int DMODEL = 512;
constexpr int NHEAD  = 8;
constexpr int DHEAD  = 64;
constexpr int DFF    = 2048;
constexpr int NLAYER = 12;
constexpr int NTOK   = BATCH * SEQ;      // 19712 = 154*128
constexpr int NQKV   = 3 * DMODEL;       // 1536
constexpr float NEGBIG = -3.402823466e38f;

typedef __attribute__((ext_vector_type(8))) short bf16x8;
typedef __attribute__((ext_vector_type(4))) float f32x4;
typedef __attribute__((ext_vector_type(8))) unsigned short u16x8;

typedef __attribute__((address_space(3))) unsigned char lds_u8;
typedef const __attribute__((address_space(1))) unsigned char g_u8;

__device__ __forceinline__ unsigned short f2bf(float f) {
    unsigned u = __float_as_uint(f);
    u = (u + 0x7FFF + ((u >> 16) & 1)) >> 16;
    return (unsigned short)u;
}

// ======================================================================
// Weight conversion (runs every launch; deterministic).
// ======================================================================
// qkv fused weight: dst[l][row][k], row<512: 0.125*qw; 512..1023: kw; else vw
__global__ __launch_bounds__(256) void conv_qkv_kernel(
    const float* __restrict__ qw, const float* __restrict__ kw,
    const float* __restrict__ vw, unsigned short* __restrict__ dst)
{
    int i4 = blockIdx.x * 256 + threadIdx.x;      // group of 4 elems
    int e = i4 * 4;                               // total 12*1536*512
    int l = e / (NQKV * DMODEL);
    int rem = e - l * (NQKV * DMODEL);
    int row = rem >> 9;          // /512
    int k   = rem & 511;
    const float* src;
    float scale = 1.0f;
    size_t lbase = (size_t)l * DMODEL * DMODEL;
    if (row < 512)       { src = qw + lbase + (size_t)row * DMODEL + k; scale = 0.125f; }
    else if (row < 1024) { src = kw + lbase + (size_t)(row - 512) * DMODEL + k; }
    else                 { src = vw + lbase + (size_t)(row - 1024) * DMODEL + k; }
    float4 v = *(const float4*)src;
    ushort4 o;
    o.x = f2bf(v.x * scale); o.y = f2bf(v.y * scale);
    o.z = f2bf(v.z * scale); o.w = f2bf(v.w * scale);
    *(ushort4*)&dst[e] = o;
}

__global__ __launch_bounds__(256) void conv_kernel(
    const float* __restrict__ src, unsigned short* __restrict__ dst)
{
    int e = (blockIdx.x * 256 + threadIdx.x) * 4;
    float4 v = *(const float4*)&src[e];
    ushort4 o;
    o.x = f2bf(v.x); o.y = f2bf(v.y); o.z = f2bf(v.z); o.w = f2bf(v.w);
    *(ushort4*)&dst[e] = o;
}

__global__ __launch_bounds__(256) void bias_qkv_kernel(
    const float* __restrict__ qb, const float* __restrict__ kb,
    const float* __restrict__ vb, float* __restrict__ dst)
{
    int e = blockIdx.x * 256 + threadIdx.x;       // 12*1536
    int l = e / NQKV;
    int row = e - l * NQKV;
    float v;
    if (row < 512)       v = qb[l * DMODEL + row] * 0.125f;
    else if (row < 1024) v = kb[l * DMODEL + row - 512];
    else                 v = vb[l * DMODEL + row - 1024];
    dst[e] = v;
}

// ======================================================================
// Embedding
// ======================================================================
__global__ __launch_bounds__(256) void embed_kernel(
    const int* __restrict__ ids, const float* __restrict__ tok,
    const float* __restrict__ pos, float* __restrict__ x)
{
    int f = blockIdx.x * 256 + threadIdx.x;
    int total = NTOK * (DMODEL / 4);
    if (f >= total) return;
    int n  = f >> 7;
    int d4 = f & 127;
    int s  = n % SEQ;
    int id = ids[n];
    float4 t = *(const float4*)&tok[(size_t)id * DMODEL + d4 * 4];
    float4 p = *(const float4*)&pos[(size_t)s  * DMODEL + d4 * 4];
    float4 o; o.x = t.x + p.x; o.y = t.y + p.y; o.z = t.z + p.z; o.w = t.w + p.w;
    *(float4*)&x[(size_t)n * DMODEL + d4 * 4] = o;
}

// ======================================================================
// LayerNorm: one wave per row of 512. Templated output dtype.
// ======================================================================
template <bool BF16OUT>
__global__ __launch_bounds__(256) void ln_kernel(
    const float* __restrict__ x, const float* __restrict__ w,
    const float* __restrict__ b, void* __restrict__ out, int nrows)
{
    int row = blockIdx.x * 4 + (threadIdx.x >> 6);
    if (row >= nrows) return;
    int ln = threadIdx.x & 63;
    const float* xr = x + (size_t)row * DMODEL + ln * 8;
    float4 v0 = *(const float4*)xr;
    float4 v1 = *(const float4*)(xr + 4);
    float va[8] = {v0.x, v0.y, v0.z, v0.w, v1.x, v1.y, v1.z, v1.w};
    float sum = 0.f, sq = 0.f;
#pragma unroll
    for (int j = 0; j < 8; ++j) { sum += va[j]; sq = fmaf(va[j], va[j], sq); }
#pragma unroll
    for (int o = 32; o; o >>= 1) { sum += __shfl_xor(sum, o); sq += __shfl_xor(sq, o); }
    float mu  = sum * (1.0f / DMODEL);
    float var = sq * (1.0f / DMODEL) - mu * mu;
    var = fmaxf(var, 0.0f);
    float inv = 1.0f / sqrtf(var + 1e-5f);
    const float* wp = w + ln * 8;
    const float* bp = b + ln * 8;
    float o8[8];
#pragma unroll
    for (int j = 0; j < 8; ++j) o8[j] = (va[j] - mu) * inv * wp[j] + bp[j];
    if (BF16OUT) {
        u16x8 pk;
#pragma unroll
        for (int j = 0; j < 8; ++j) pk[j] = f2bf(o8[j]);
        *(u16x8*)((unsigned short*)out + (size_t)row * DMODEL + ln * 8) = pk;
    } else {
        float* op = (float*)out + (size_t)row * DMODEL + ln * 8;
        *(float4*)op       = make_float4(o8[0], o8[1], o8[2], o8[3]);
        *(float4*)(op + 4) = make_float4(o8[4], o8[5], o8[6], o8[7]);
    }
}

// ======================================================================
// bf16 MFMA GEMM (m97 structure): C[M,N] = A[M,K] (bf16) * W[N,K]^T (bf16)
// 128x128 tile, BK=32, 256 threads (4 waves, 2x2), 4x4 16x16x32 frags/wave.
// MODE 0: +bias (f32 out); 2: quickGELU(+bias) (bf16 out); 3: +bias+R (f32 out)
// ======================================================================
template <int MODE, bool OUTBF>
__global__ __launch_bounds__(256) void gemm_bf16(
    const unsigned short* __restrict__ A, const unsigned short* __restrict__ W,
    const float* __restrict__ bias, const float* __restrict__ R,
    void* __restrict__ Cout, int M, int N, int K)
{
    __shared__ short As[128 * 32];
    __shared__ short Bs[128 * 32];
    const int tid  = threadIdx.x;
    const int wid  = tid >> 6;
    const int lane = tid & 63;
    const int wr   = wid >> 1;          // wave row 0..1
    const int wc   = wid & 1;           // wave col 0..1
    const int m0 = blockIdx.y * 128;
    const int n0 = blockIdx.x * 128;

    // staging indices (linear LDS <-> lane order)
    const int srow = tid >> 2;          // 0..63
    const int scol = (tid & 3) * 8;     // k offset in elems
    const unsigned short* Ap = A + (size_t)(m0 + srow) * K + scol;
    const unsigned short* Wp = W + (size_t)(n0 + srow) * K + scol;
    const size_t rstride = (size_t)64 * K;
    // wave-uniform LDS bases (bytes): chunk c -> c*4096 + wid*1024
    short* ldsA0 = &As[wid * 512];
    short* ldsA1 = &As[2048 + wid * 512];
    short* ldsB0 = &Bs[wid * 512];
    short* ldsB1 = &Bs[2048 + wid * 512];

    f32x4 acc[4][4];
#pragma unroll
    for (int i = 0; i < 4; ++i)
#pragma unroll
        for (int j = 0; j < 4; ++j) acc[i][j] = (f32x4){0.f, 0.f, 0.f, 0.f};

    const int lhi = lane >> 4;   // 0..3
    const int llo = lane & 15;
    // fragment LDS offsets (in shorts)
    int aoff[4], boff[4];
#pragma unroll
    for (int i = 0; i < 4; ++i) {
        aoff[i] = (wr * 64 + i * 16 + llo) * 32 + lhi * 8;
        boff[i] = (wc * 64 + i * 16 + llo) * 32 + lhi * 8;
    }

    for (int k0 = 0; k0 < K; k0 += 32) {
        __syncthreads();
        __builtin_amdgcn_global_load_lds((g_u8*)(Ap + k0),            (lds_u8*)ldsA0, 16, 0, 0);
        __builtin_amdgcn_global_load_lds((g_u8*)(Ap + rstride + k0),  (lds_u8*)ldsA1, 16, 0, 0);
        __builtin_amdgcn_global_load_lds((g_u8*)(Wp + k0),            (lds_u8*)ldsB0, 16, 0, 0);
        __builtin_amdgcn_global_load_lds((g_u8*)(Wp + rstride + k0),  (lds_u8*)ldsB1, 16, 0, 0);
        __syncthreads();
        bf16x8 af[4], bfr[4];
#pragma unroll
        for (int i = 0; i < 4; ++i) af[i]  = *(const bf16x8*)&As[aoff[i]];
#pragma unroll
        for (int j = 0; j < 4; ++j) bfr[j] = *(const bf16x8*)&Bs[boff[j]];
#pragma unroll
        for (int i = 0; i < 4; ++i)
#pragma unroll
            for (int j = 0; j < 4; ++j)
                acc[i][j] = __builtin_amdgcn_mfma_f32_16x16x32_bf16(af[i], bfr[j], acc[i][j], 0, 0, 0);
    }

    // epilogue
#pragma unroll
    for (int j = 0; j < 4; ++j) {
        int col = n0 + wc * 64 + j * 16 + llo;
        float bv = bias[col];
#pragma unroll
        for (int i = 0; i < 4; ++i) {
            int row0 = m0 + wr * 64 + i * 16 + lhi * 4;
#pragma unroll
            for (int r = 0; r < 4; ++r) {
                size_t idx = (size_t)(row0 + r) * N + col;
                float o = acc[i][j][r] + bv;
                if (MODE == 2) o = o / (1.0f + __expf(-1.702f * o));
                if (MODE == 3) o += R[idx];
                if (OUTBF) ((unsigned short*)Cout)[idx] = f2bf(o);
                else       ((float*)Cout)[idx] = o;
            }
        }
    }
}

// ======================================================================
// Attention (fp32): one block per (b,h), qkv fused input [NTOK][1536].
// Writes bf16 output [NTOK][512] for the o-projection.
// ======================================================================
__global__ __launch_bounds__(256) void attn_kernel(
    const float* __restrict__ qkv, const int* __restrict__ amask,
    unsigned short* __restrict__ out)
{
    const int bh = blockIdx.x;
    const int b = bh / NHEAD;
    const int h = bh % NHEAD;
    __shared__ float qs[SEQ][DHEAD];
    __shared__ float ks[SEQ][DHEAD + 1];
    __shared__ float vs[SEQ][DHEAD];
    __shared__ float ss[SEQ][SEQ + 3];
    __shared__ float padm[SEQ];
    const int tid = threadIdx.x;

    for (int f = tid; f < SEQ * (DHEAD / 4); f += 256) {
        int s  = f >> 4;
        int d4 = (f & 15) * 4;
        size_t g = ((size_t)(b * SEQ + s) * NQKV) + h * DHEAD + d4;
        float4 qv = *(const float4*)&qkv[g];
        float4 kv = *(const float4*)&qkv[g + 512];
        float4 vv = *(const float4*)&qkv[g + 1024];
        qs[s][d4] = qv.x; qs[s][d4+1] = qv.y; qs[s][d4+2] = qv.z; qs[s][d4+3] = qv.w;
        ks[s][d4] = kv.x; ks[s][d4+1] = kv.y; ks[s][d4+2] = kv.z; ks[s][d4+3] = kv.w;
        vs[s][d4] = vv.x; vs[s][d4+1] = vv.y; vs[s][d4+2] = vv.z; vs[s][d4+3] = vv.w;
    }
    for (int s = tid; s < SEQ; s += 256)
        padm[s] = (1.0f - (float)amask[b * SEQ + s]) * NEGBIG;
    __syncthreads();

    for (int idx = tid; idx < SEQ * SEQ; idx += 256) {
        int qi = idx / SEQ, ki = idx % SEQ;
        float acc = 0.f;
#pragma unroll 8
        for (int d = 0; d < DHEAD; ++d) acc = fmaf(qs[qi][d], ks[ki][d], acc);
        float m = (ki > qi) ? NEGBIG : 0.0f;
        ss[qi][ki] = acc + m + padm[ki];
    }
    __syncthreads();

    const int wv = tid >> 6;
    const int ln = tid & 63;
    for (int qi = wv; qi < SEQ; qi += 4) {
        float s0 = ss[qi][ln];
        float s1 = (ln + 64 < SEQ) ? ss[qi][ln + 64] : -INFINITY;
        float m = fmaxf(s0, s1);
#pragma unroll
        for (int o = 32; o; o >>= 1) m = fmaxf(m, __shfl_xor(m, o));
        float e0 = expf(s0 - m);
        float e1 = (ln + 64 < SEQ) ? expf(s1 - m) : 0.0f;
        float t = e0 + e1;
#pragma unroll
        for (int o = 32; o; o >>= 1) t += __shfl_xor(t, o);
        float r = 1.0f / t;
        ss[qi][ln] = e0 * r;
        if (ln + 64 < SEQ) ss[qi][ln + 64] = e1 * r;
    }
    __syncthreads();

    for (int idx = tid; idx < SEQ * DHEAD; idx += 256) {
        int qi = idx >> 6;
        int d  = idx & 63;
        float acc = 0.f;
        for (int ki = 0; ki < SEQ; ++ki) acc = fmaf(ss[qi][ki], vs[ki][d], acc);
        out[((size_t)(b * SEQ + qi) * DMODEL) + h * DHEAD + d] = f2bf(acc);
    }
}

// ======================================================================
// Pooled output
// ======================================================================
__global__ __launch_bounds__(64) void pool_kernel(
    const int* __restrict__ ids, const float* __restrict__ lh,
    float* __restrict__ pooled)
{
    int b = blockIdx.x;
    int ln = threadIdx.x;
    __shared__ int sidx;
    if (ln == 0) {
        int best = ids[b * SEQ]; int bi = 0;
        for (int s = 1; s < SEQ; ++s) {
            int vv = ids[b * SEQ + s];
            if (vv > best) { best = vv; bi = s; }
        }
        sidx = bi;
    }
    __syncthreads();
    const float* src = lh + ((size_t)(b * SEQ + sidx)) * DMODEL + ln * 8;
    float* dst = pooled + (size_t)b * DMODEL + ln * 8;
    float4 a = *(const float4*)src;
    float4 c = *(const float4*)(src + 4);
    *(float4*)dst       = a;
    *(float4*)(dst + 4) = c;
}

// ======================================================================
extern "C" void kernel_launch(void* const* d_in, const int* in_sizes, int n_in,
                              void* d_out, int out_size, void* d_ws, size_t ws_size,
                              hipStream_t stream) {
    const int*   ids   = (const int*)d_in[0];
    const int*   amask = (const int*)d_in[1];
    const float* tok   = (const float*)d_in[2];
    const float* pos   = (const float*)d_in[3];
    const float* ln1w  = (const float*)d_in[4];
    const float* ln1b  = (const float*)d_in[5];
    const float* qw    = (const float*)d_in[6];
    const float* qbias = (const float*)d_in[7];
    const float* kw    = (const float*)d_in[8];
    const float* kbias = (const float*)d_in[9];
    const float* vw    = (const float*)d_in[10];
    const float* vbias = (const float*)d_in[11];
    const float* ow    = (const float*)d_in[12];
    const float* obias = (const float*)d_in[13];
    const float* ln2w  = (const float*)d_in[14];
    const float* ln2b  = (const float*)d_in[15];
    const float* f1w   = (const float*)d_in[16];
    const float* f1b   = (const float*)d_in[17];
    const float* f2w   = (const float*)d_in[18];
    const float* f2b   = (const float*)d_in[19];
    const float* lnfw  = (const float*)d_in[20];
    const float* lnfb  = (const float*)d_in[21];

    char* p = (char*)d_ws;
    float* x = (float*)p;                 p += (size_t)NTOK * DMODEL * 4;
    unsigned short* hbuf = (unsigned short*)p; p += (size_t)NTOK * DMODEL * 2;
    float* qkv = (float*)p;               p += (size_t)NTOK * NQKV * 4;
    unsigned short* ao = (unsigned short*)p;   p += (size_t)NTOK * DMODEL * 2;
    unsigned short* ff = (unsigned short*)p;   p += (size_t)NTOK * DFF * 2;
    unsigned short* wqkv = (unsigned short*)p; p += (size_t)NLAYER * NQKV * DMODEL * 2;
    unsigned short* wo   = (unsigned short*)p; p += (size_t)NLAYER * DMODEL * DMODEL * 2;
    unsigned short* wf1  = (unsigned short*)p; p += (size_t)NLAYER * DFF * DMODEL * 2;
    unsigned short* wf2  = (unsigned short*)p; p += (size_t)NLAYER * DMODEL * DFF * 2;
    float* bqkv = (float*)p;              p += (size_t)NLAYER * NQKV * 4;

    // ---- weight conversion (per launch; ~226 MB traffic ≈ 45 µs) ----
    conv_qkv_kernel<<<(NLAYER * NQKV * DMODEL / 4) / 256, 256, 0, stream>>>(qw, kw, vw, wqkv);
    conv_kernel<<<(NLAYER * DMODEL * DMODEL / 4) / 256, 256, 0, stream>>>(ow, wo);
    conv_kernel<<<(NLAYER * DFF * DMODEL / 4) / 256, 256, 0, stream>>>(f1w, wf1);
    conv_kernel<<<(NLAYER * DMODEL * DFF / 4) / 256, 256, 0, stream>>>(f2w, wf2);
    bias_qkv_kernel<<<(NLAYER * NQKV) / 256, 256, 0, stream>>>(qbias, kbias, vbias, bqkv);

    embed_kernel<<<(NTOK * (DMODEL / 4) + 255) / 256, 256, 0, stream>>>(ids, tok, pos, x);

    dim3 gqkv(NQKV / 128, NTOK / 128);    // (12, 154)
    dim3 g512(DMODEL / 128, NTOK / 128);  // (4, 154)
    dim3 g2048(DFF / 128, NTOK / 128);    // (16, 154)

    for (int l = 0; l < NLAYER; ++l) {
        const size_t wD2 = (size_t)l * DMODEL * DMODEL;
        const size_t wDF = (size_t)l * DFF * DMODEL;
        const size_t oD  = (size_t)l * DMODEL;
        const size_t oF  = (size_t)l * DFF;

        ln_kernel<true><<<NTOK / 4, 256, 0, stream>>>(x, ln1w + oD, ln1b + oD, hbuf, NTOK);
        gemm_bf16<0, false><<<gqkv, 256, 0, stream>>>(
            hbuf, wqkv + (size_t)l * NQKV * DMODEL, bqkv + (size_t)l * NQKV, nullptr,
            qkv, NTOK, NQKV, DMODEL);
        attn_kernel<<<BATCH * NHEAD, 256, 0, stream>>>(qkv, amask, ao);
        gemm_bf16<3, false><<<g512, 256, 0, stream>>>(
            ao, wo + wD2, obias + oD, x, x, NTOK, DMODEL, DMODEL);
        ln_kernel<true><<<NTOK / 4, 256, 0, stream>>>(x, ln2w + oD, ln2b + oD, hbuf, NTOK);
        gemm_bf16<2, true><<<g2048, 256, 0, stream>>>(
            hbuf, wf1 + wDF, f1b + oF, nullptr, ff, NTOK, DFF, DMODEL);
        gemm_bf16<3, false><<<g512, 256, 0, stream>>>(
            ff, wf2 + wDF, f2b + oD, x, x, NTOK, DMODEL, DFF);
    }

    float* outf = (float*)d_out;
    ln_kernel<false><<<NTOK / 4, 256, 0, stream>>>(x, lnfw, lnfb, outf, NTOK);
    pool_kernel<<<BATCH, 64, 0, stream>>>(ids, outf, outf + (size_t)NTOK * DMODEL);
}

// Round 4
// 4873.410 us; speedup vs baseline: 5.0365x; 1.5663x over previous
//
#include <hip/hip_runtime.h>
#include <math.h>

// ---- Problem constants ----
constexpr int BATCH  = 256;
constexpr int SEQ    = 77;
constexpr int DMODEL = 512;
constexpr int NHEAD  = 8;
constexpr int DHEAD  = 64;
constexpr int DFF    = 2048;
constexpr int NLAYER = 12;
constexpr int NTOK   = BATCH * SEQ;      // 19712 = 154*128
constexpr int NQKV   = 3 * DMODEL;       // 1536
constexpr float NEGBIG = -3.402823466e38f;

typedef __attribute__((ext_vector_type(8))) short bf16x8;
typedef __attribute__((ext_vector_type(4))) float f32x4;
typedef __attribute__((ext_vector_type(8))) unsigned short u16x8;

typedef __attribute__((address_space(3))) unsigned char lds_u8;
typedef const __attribute__((address_space(1))) unsigned char g_u8;

__device__ __forceinline__ unsigned short f2bf(float f) {
    unsigned u = __float_as_uint(f);
    u = (u + 0x7FFF + ((u >> 16) & 1)) >> 16;
    return (unsigned short)u;
}

// ======================================================================
// Weight conversion (runs every launch; deterministic).
// ======================================================================
__global__ __launch_bounds__(256) void conv_qkv_kernel(
    const float* __restrict__ qw, const float* __restrict__ kw,
    const float* __restrict__ vw, unsigned short* __restrict__ dst)
{
    int i4 = blockIdx.x * 256 + threadIdx.x;
    int e = i4 * 4;
    int l = e / (NQKV * DMODEL);
    int rem = e - l * (NQKV * DMODEL);
    int row = rem >> 9;
    int k   = rem & 511;
    const float* src;
    float scale = 1.0f;
    size_t lbase = (size_t)l * DMODEL * DMODEL;
    if (row < 512)       { src = qw + lbase + (size_t)row * DMODEL + k; scale = 0.125f; }
    else if (row < 1024) { src = kw + lbase + (size_t)(row - 512) * DMODEL + k; }
    else                 { src = vw + lbase + (size_t)(row - 1024) * DMODEL + k; }
    float4 v = *(const float4*)src;
    ushort4 o;
    o.x = f2bf(v.x * scale); o.y = f2bf(v.y * scale);
    o.z = f2bf(v.z * scale); o.w = f2bf(v.w * scale);
    *(ushort4*)&dst[e] = o;
}

__global__ __launch_bounds__(256) void conv_kernel(
    const float* __restrict__ src, unsigned short* __restrict__ dst)
{
    int e = (blockIdx.x * 256 + threadIdx.x) * 4;
    float4 v = *(const float4*)&src[e];
    ushort4 o;
    o.x = f2bf(v.x); o.y = f2bf(v.y); o.z = f2bf(v.z); o.w = f2bf(v.w);
    *(ushort4*)&dst[e] = o;
}

__global__ __launch_bounds__(256) void bias_qkv_kernel(
    const float* __restrict__ qb, const float* __restrict__ kb,
    const float* __restrict__ vb, float* __restrict__ dst)
{
    int e = blockIdx.x * 256 + threadIdx.x;
    int l = e / NQKV;
    int row = e - l * NQKV;
    float v;
    if (row < 512)       v = qb[l * DMODEL + row] * 0.125f;
    else if (row < 1024) v = kb[l * DMODEL + row - 512];
    else                 v = vb[l * DMODEL + row - 1024];
    dst[e] = v;
}

// ======================================================================
// Embedding
// ======================================================================
__global__ __launch_bounds__(256) void embed_kernel(
    const int* __restrict__ ids, const float* __restrict__ tok,
    const float* __restrict__ pos, float* __restrict__ x)
{
    int f = blockIdx.x * 256 + threadIdx.x;
    int total = NTOK * (DMODEL / 4);
    if (f >= total) return;
    int n  = f >> 7;
    int d4 = f & 127;
    int s  = n % SEQ;
    int id = ids[n];
    float4 t = *(const float4*)&tok[(size_t)id * DMODEL + d4 * 4];
    float4 p = *(const float4*)&pos[(size_t)s  * DMODEL + d4 * 4];
    float4 o; o.x = t.x + p.x; o.y = t.y + p.y; o.z = t.z + p.z; o.w = t.w + p.w;
    *(float4*)&x[(size_t)n * DMODEL + d4 * 4] = o;
}

// ======================================================================
// LayerNorm: one wave per row of 512. Templated output dtype.
// ======================================================================
template <bool BF16OUT>
__global__ __launch_bounds__(256) void ln_kernel(
    const float* __restrict__ x, const float* __restrict__ w,
    const float* __restrict__ b, void* __restrict__ out, int nrows)
{
    int row = blockIdx.x * 4 + (threadIdx.x >> 6);
    if (row >= nrows) return;
    int ln = threadIdx.x & 63;
    const float* xr = x + (size_t)row * DMODEL + ln * 8;
    float4 v0 = *(const float4*)xr;
    float4 v1 = *(const float4*)(xr + 4);
    float va[8] = {v0.x, v0.y, v0.z, v0.w, v1.x, v1.y, v1.z, v1.w};
    float sum = 0.f, sq = 0.f;
#pragma unroll
    for (int j = 0; j < 8; ++j) { sum += va[j]; sq = fmaf(va[j], va[j], sq); }
#pragma unroll
    for (int o = 32; o; o >>= 1) { sum += __shfl_xor(sum, o); sq += __shfl_xor(sq, o); }
    float mu  = sum * (1.0f / DMODEL);
    float var = sq * (1.0f / DMODEL) - mu * mu;
    var = fmaxf(var, 0.0f);
    float inv = 1.0f / sqrtf(var + 1e-5f);
    const float* wp = w + ln * 8;
    const float* bp = b + ln * 8;
    float o8[8];
#pragma unroll
    for (int j = 0; j < 8; ++j) o8[j] = (va[j] - mu) * inv * wp[j] + bp[j];
    if (BF16OUT) {
        u16x8 pk;
#pragma unroll
        for (int j = 0; j < 8; ++j) pk[j] = f2bf(o8[j]);
        *(u16x8*)((unsigned short*)out + (size_t)row * DMODEL + ln * 8) = pk;
    } else {
        float* op = (float*)out + (size_t)row * DMODEL + ln * 8;
        *(float4*)op       = make_float4(o8[0], o8[1], o8[2], o8[3]);
        *(float4*)(op + 4) = make_float4(o8[4], o8[5], o8[6], o8[7]);
    }
}

// ======================================================================
// bf16 MFMA GEMM (m97 structure)
// ======================================================================
template <int MODE, bool OUTBF>
__global__ __launch_bounds__(256) void gemm_bf16(
    const unsigned short* __restrict__ A, const unsigned short* __restrict__ W,
    const float* __restrict__ bias, const float* __restrict__ R,
    void* __restrict__ Cout, int M, int N, int K)
{
    __shared__ short As[128 * 32];
    __shared__ short Bs[128 * 32];
    const int tid  = threadIdx.x;
    const int wid  = tid >> 6;
    const int lane = tid & 63;
    const int wr   = wid >> 1;
    const int wc   = wid & 1;
    const int m0 = blockIdx.y * 128;
    const int n0 = blockIdx.x * 128;

    const int srow = tid >> 2;
    const int scol = (tid & 3) * 8;
    const unsigned short* Ap = A + (size_t)(m0 + srow) * K + scol;
    const unsigned short* Wp = W + (size_t)(n0 + srow) * K + scol;
    const size_t rstride = (size_t)64 * K;
    short* ldsA0 = &As[wid * 512];
    short* ldsA1 = &As[2048 + wid * 512];
    short* ldsB0 = &Bs[wid * 512];
    short* ldsB1 = &Bs[2048 + wid * 512];

    f32x4 acc[4][4];
#pragma unroll
    for (int i = 0; i < 4; ++i)
#pragma unroll
        for (int j = 0; j < 4; ++j) acc[i][j] = (f32x4){0.f, 0.f, 0.f, 0.f};

    const int lhi = lane >> 4;
    const int llo = lane & 15;
    int aoff[4], boff[4];
#pragma unroll
    for (int i = 0; i < 4; ++i) {
        aoff[i] = (wr * 64 + i * 16 + llo) * 32 + lhi * 8;
        boff[i] = (wc * 64 + i * 16 + llo) * 32 + lhi * 8;
    }

    for (int k0 = 0; k0 < K; k0 += 32) {
        __syncthreads();
        __builtin_amdgcn_global_load_lds((g_u8*)(Ap + k0),            (lds_u8*)ldsA0, 16, 0, 0);
        __builtin_amdgcn_global_load_lds((g_u8*)(Ap + rstride + k0),  (lds_u8*)ldsA1, 16, 0, 0);
        __builtin_amdgcn_global_load_lds((g_u8*)(Wp + k0),            (lds_u8*)ldsB0, 16, 0, 0);
        __builtin_amdgcn_global_load_lds((g_u8*)(Wp + rstride + k0),  (lds_u8*)ldsB1, 16, 0, 0);
        __syncthreads();
        bf16x8 af[4], bfr[4];
#pragma unroll
        for (int i = 0; i < 4; ++i) af[i]  = *(const bf16x8*)&As[aoff[i]];
#pragma unroll
        for (int j = 0; j < 4; ++j) bfr[j] = *(const bf16x8*)&Bs[boff[j]];
#pragma unroll
        for (int i = 0; i < 4; ++i)
#pragma unroll
            for (int j = 0; j < 4; ++j)
                acc[i][j] = __builtin_amdgcn_mfma_f32_16x16x32_bf16(af[i], bfr[j], acc[i][j], 0, 0, 0);
    }

#pragma unroll
    for (int j = 0; j < 4; ++j) {
        int col = n0 + wc * 64 + j * 16 + llo;
        float bv = bias[col];
#pragma unroll
        for (int i = 0; i < 4; ++i) {
            int row0 = m0 + wr * 64 + i * 16 + lhi * 4;
#pragma unroll
            for (int r = 0; r < 4; ++r) {
                size_t idx = (size_t)(row0 + r) * N + col;
                float o = acc[i][j][r] + bv;
                if (MODE == 2) o = o / (1.0f + __expf(-1.702f * o));
                if (MODE == 3) o += R[idx];
                if (OUTBF) ((unsigned short*)Cout)[idx] = f2bf(o);
                else       ((float*)Cout)[idx] = o;
            }
        }
    }
}

// ======================================================================
// MFMA attention: one block per (b,h), 4 waves, 68.2 KB LDS (2 blocks/CU).
// LDS plan (bytes):
//   [0,10240)      Qs: 80 rows x 128 B (8 chunks, XOR (r&7)<<4 - bijective)
//   [10240,20480)  Ks: same layout
//   [0,16384)      Vt: 64 rows x 256 B (16 chunks, XOR (d&7)<<4 - bijective)
//                  ^ overlaps Qs/Ks; staged AFTER QK^T phase barrier
//   [20480,40960)  Pb: 80 rows x 256 B (16 chunks, XOR (q&7)<<4)
//   [40960,67840)  ss: f32 [80][84]
//   [67840,68160)  padm
// ======================================================================
__global__ __launch_bounds__(256) void attn_mfma_kernel(
    const float* __restrict__ qkv, const int* __restrict__ amask,
    unsigned short* __restrict__ out)
{
    const int bh = blockIdx.x;
    const int b = bh >> 3;
    const int h = bh & 7;
    __shared__ __align__(16) char smem[68160];
    char* Qs = smem;
    char* Ks = smem + 10240;
    char* Vt = smem;                 // overlaps Qs/Ks (used after QK^T)
    char* Pb = smem + 20480;
    float* ss = (float*)(smem + 40960);   // [80][84]
    float* padm = (float*)(smem + 67840);
    const int tid  = threadIdx.x;
    const int wid  = tid >> 6;
    const int lane = tid & 63;
    const int llo  = lane & 15;
    const int lhi  = lane >> 4;

    // ---- stage Q,K (bf16, swizzled 16B chunks), rows 77..79 zeroed ----
    for (int f = tid; f < 640; f += 256) {
        int r = f >> 3, c = f & 7;
        bf16x8 pq, pk;
        if (r < SEQ) {
            size_t g = ((size_t)(b * SEQ + r)) * NQKV + h * DHEAD + c * 8;
            float4 q0 = *(const float4*)&qkv[g];
            float4 q1 = *(const float4*)&qkv[g + 4];
            float4 k0 = *(const float4*)&qkv[g + 512];
            float4 k1 = *(const float4*)&qkv[g + 516];
            pq[0] = (short)f2bf(q0.x); pq[1] = (short)f2bf(q0.y);
            pq[2] = (short)f2bf(q0.z); pq[3] = (short)f2bf(q0.w);
            pq[4] = (short)f2bf(q1.x); pq[5] = (short)f2bf(q1.y);
            pq[6] = (short)f2bf(q1.z); pq[7] = (short)f2bf(q1.w);
            pk[0] = (short)f2bf(k0.x); pk[1] = (short)f2bf(k0.y);
            pk[2] = (short)f2bf(k0.z); pk[3] = (short)f2bf(k0.w);
            pk[4] = (short)f2bf(k1.x); pk[5] = (short)f2bf(k1.y);
            pk[6] = (short)f2bf(k1.z); pk[7] = (short)f2bf(k1.w);
        } else {
#pragma unroll
            for (int j = 0; j < 8; ++j) { pq[j] = 0; pk[j] = 0; }
        }
        int byte = r * 128 + ((c * 16) ^ ((r & 7) << 4));
        *(bf16x8*)(Qs + byte) = pq;
        *(bf16x8*)(Ks + byte) = pk;
    }
    for (int s = tid; s < SEQ; s += 256)
        padm[s] = (1.0f - (float)amask[b * SEQ + s]) * NEGBIG;
    __syncthreads();

    // ---- QK^T: 25 tiles of 16x16, K=64 (2 MFMA each) ----
    for (int t = wid; t < 25; t += 4) {
        int rt = t / 5, ct = t % 5;
        int ar = rt * 16 + llo;
        int br = ct * 16 + llo;
        int aswz = (ar & 7) << 4;
        int bswz = (br & 7) << 4;
        bf16x8 a0 = *(const bf16x8*)(Qs + ar * 128 + ((lhi * 16) ^ aswz));
        bf16x8 a1 = *(const bf16x8*)(Qs + ar * 128 + (((lhi + 4) * 16) ^ aswz));
        bf16x8 b0 = *(const bf16x8*)(Ks + br * 128 + ((lhi * 16) ^ bswz));
        bf16x8 b1 = *(const bf16x8*)(Ks + br * 128 + (((lhi + 4) * 16) ^ bswz));
        f32x4 acc = (f32x4){0.f, 0.f, 0.f, 0.f};
        acc = __builtin_amdgcn_mfma_f32_16x16x32_bf16(a0, b0, acc, 0, 0, 0);
        acc = __builtin_amdgcn_mfma_f32_16x16x32_bf16(a1, b1, acc, 0, 0, 0);
        int ki = ct * 16 + llo;
#pragma unroll
        for (int r = 0; r < 4; ++r) {
            int qi = rt * 16 + lhi * 4 + r;
            ss[qi * 84 + ki] = (ki > qi || ki >= SEQ) ? NEGBIG : (acc[r] + padm[ki]);
        }
    }
    __syncthreads();   // Qs/Ks reads done; ss visible

    // ---- stage V transposed into Vt[d][s] (row stride 256 B, 16 chunks) ----
    for (int f = tid; f < SEQ * 16; f += 256) {
        int s = f >> 4, d4 = (f & 15) * 4;
        float4 v = *(const float4*)&qkv[((size_t)(b * SEQ + s)) * NQKV + 1024 + h * DHEAD + d4];
        float va[4] = {v.x, v.y, v.z, v.w};
        int chunk16 = (s >> 3) * 16, within = (s & 7) * 2;
#pragma unroll
        for (int j = 0; j < 4; ++j) {
            int d = d4 + j;
            int byte = d * 256 + (chunk16 ^ ((d & 7) << 4)) + within;
            *(short*)(Vt + byte) = (short)f2bf(va[j]);
        }
    }
    // zero-pad Vt s = 77..95
    for (int f = tid; f < 64 * 19; f += 256) {
        int d = f & 63, s = 77 + (f >> 6);
        int byte = d * 256 + (((s >> 3) * 16) ^ ((d & 7) << 4)) + (s & 7) * 2;
        *(short*)(Vt + byte) = 0;
    }

    // ---- softmax (rows striped over waves), write bf16 P (256 B rows) ----
    for (int qi = wid; qi < SEQ; qi += 4) {
        float s0 = ss[qi * 84 + lane];
        float s1 = (lane < 16) ? ss[qi * 84 + 64 + lane] : NEGBIG;
        float m = fmaxf(s0, s1);
#pragma unroll
        for (int o = 32; o; o >>= 1) m = fmaxf(m, __shfl_xor(m, o));
        float e0 = __expf(s0 - m);
        float e1 = (lane < 16) ? __expf(s1 - m) : 0.f;
        float tsum = e0 + e1;
#pragma unroll
        for (int o = 32; o; o >>= 1) tsum += __shfl_xor(tsum, o);
        float rinv = 1.0f / tsum;
        int qswz = (qi & 7) << 4;
        {
            int col = lane;
            int byte = qi * 256 + (((col >> 3) * 16) ^ qswz) + (col & 7) * 2;
            *(short*)(Pb + byte) = (short)f2bf(e0 * rinv);
        }
        if (lane < 32) {
            int col = 64 + lane;
            float p = (lane < 16) ? e1 * rinv : 0.f;
            int byte = qi * 256 + (((col >> 3) * 16) ^ qswz) + (col & 7) * 2;
            *(short*)(Pb + byte) = (short)f2bf(p);
        }
    }
    __syncthreads();   // Vt + Pb ready

    // ---- PV: O[80][64], 20 tiles, K=96 (3 MFMA each) ----
    for (int t = wid; t < 20; t += 4) {
        int rt = t >> 2, ct = t & 3;
        int ar = rt * 16 + llo;
        int br = ct * 16 + llo;
        int aswz = (ar & 7) << 4;
        int bswz = (br & 7) << 4;
        f32x4 acc = (f32x4){0.f, 0.f, 0.f, 0.f};
#pragma unroll
        for (int kc = 0; kc < 3; ++kc) {
            bf16x8 af  = *(const bf16x8*)(Pb + ar * 256 + (((kc * 4 + lhi) * 16) ^ aswz));
            bf16x8 bf_ = *(const bf16x8*)(Vt + br * 256 + (((kc * 4 + lhi) * 16) ^ bswz));
            acc = __builtin_amdgcn_mfma_f32_16x16x32_bf16(af, bf_, acc, 0, 0, 0);
        }
        int d = ct * 16 + llo;
#pragma unroll
        for (int r = 0; r < 4; ++r) {
            int qi = rt * 16 + lhi * 4 + r;
            if (qi < SEQ)
                out[((size_t)(b * SEQ + qi)) * DMODEL + h * DHEAD + d] = f2bf(acc[r]);
        }
    }
}

// ======================================================================
// Pooled output
// ======================================================================
__global__ __launch_bounds__(64) void pool_kernel(
    const int* __restrict__ ids, const float* __restrict__ lh,
    float* __restrict__ pooled)
{
    int b = blockIdx.x;
    int ln = threadIdx.x;
    __shared__ int sidx;
    if (ln == 0) {
        int best = ids[b * SEQ]; int bi = 0;
        for (int s = 1; s < SEQ; ++s) {
            int vv = ids[b * SEQ + s];
            if (vv > best) { best = vv; bi = s; }
        }
        sidx = bi;
    }
    __syncthreads();
    const float* src = lh + ((size_t)(b * SEQ + sidx)) * DMODEL + ln * 8;
    float* dst = pooled + (size_t)b * DMODEL + ln * 8;
    float4 a = *(const float4*)src;
    float4 c = *(const float4*)(src + 4);
    *(float4*)dst       = a;
    *(float4*)(dst + 4) = c;
}

// ======================================================================
extern "C" void kernel_launch(void* const* d_in, const int* in_sizes, int n_in,
                              void* d_out, int out_size, void* d_ws, size_t ws_size,
                              hipStream_t stream) {
    const int*   ids   = (const int*)d_in[0];
    const int*   amask = (const int*)d_in[1];
    const float* tok   = (const float*)d_in[2];
    const float* pos   = (const float*)d_in[3];
    const float* ln1w  = (const float*)d_in[4];
    const float* ln1b  = (const float*)d_in[5];
    const float* qw    = (const float*)d_in[6];
    const float* qbias = (const float*)d_in[7];
    const float* kw    = (const float*)d_in[8];
    const float* kbias = (const float*)d_in[9];
    const float* vw    = (const float*)d_in[10];
    const float* vbias = (const float*)d_in[11];
    const float* ow    = (const float*)d_in[12];
    const float* obias = (const float*)d_in[13];
    const float* ln2w  = (const float*)d_in[14];
    const float* ln2b  = (const float*)d_in[15];
    const float* f1w   = (const float*)d_in[16];
    const float* f1b   = (const float*)d_in[17];
    const float* f2w   = (const float*)d_in[18];
    const float* f2b   = (const float*)d_in[19];
    const float* lnfw  = (const float*)d_in[20];
    const float* lnfb  = (const float*)d_in[21];

    char* p = (char*)d_ws;
    float* x = (float*)p;                 p += (size_t)NTOK * DMODEL * 4;
    unsigned short* hbuf = (unsigned short*)p; p += (size_t)NTOK * DMODEL * 2;
    float* qkv = (float*)p;               p += (size_t)NTOK * NQKV * 4;
    unsigned short* ao = (unsigned short*)p;   p += (size_t)NTOK * DMODEL * 2;
    unsigned short* ff = (unsigned short*)p;   p += (size_t)NTOK * DFF * 2;
    unsigned short* wqkv = (unsigned short*)p; p += (size_t)NLAYER * NQKV * DMODEL * 2;
    unsigned short* wo   = (unsigned short*)p; p += (size_t)NLAYER * DMODEL * DMODEL * 2;
    unsigned short* wf1  = (unsigned short*)p; p += (size_t)NLAYER * DFF * DMODEL * 2;
    unsigned short* wf2  = (unsigned short*)p; p += (size_t)NLAYER * DMODEL * DFF * 2;
    float* bqkv = (float*)p;              p += (size_t)NLAYER * NQKV * 4;

    conv_qkv_kernel<<<(NLAYER * NQKV * DMODEL / 4) / 256, 256, 0, stream>>>(qw, kw, vw, wqkv);
    conv_kernel<<<(NLAYER * DMODEL * DMODEL / 4) / 256, 256, 0, stream>>>(ow, wo);
    conv_kernel<<<(NLAYER * DFF * DMODEL / 4) / 256, 256, 0, stream>>>(f1w, wf1);
    conv_kernel<<<(NLAYER * DMODEL * DFF / 4) / 256, 256, 0, stream>>>(f2w, wf2);
    bias_qkv_kernel<<<(NLAYER * NQKV) / 256, 256, 0, stream>>>(qbias, kbias, vbias, bqkv);

    embed_kernel<<<(NTOK * (DMODEL / 4) + 255) / 256, 256, 0, stream>>>(ids, tok, pos, x);

    dim3 gqkv(NQKV / 128, NTOK / 128);
    dim3 g512(DMODEL / 128, NTOK / 128);
    dim3 g2048(DFF / 128, NTOK / 128);

    for (int l = 0; l < NLAYER; ++l) {
        const size_t wD2 = (size_t)l * DMODEL * DMODEL;
        const size_t wDF = (size_t)l * DFF * DMODEL;
        const size_t oD  = (size_t)l * DMODEL;
        const size_t oF  = (size_t)l * DFF;

        ln_kernel<true><<<NTOK / 4, 256, 0, stream>>>(x, ln1w + oD, ln1b + oD, hbuf, NTOK);
        gemm_bf16<0, false><<<gqkv, 256, 0, stream>>>(
            hbuf, wqkv + (size_t)l * NQKV * DMODEL, bqkv + (size_t)l * NQKV, nullptr,
            qkv, NTOK, NQKV, DMODEL);
        attn_mfma_kernel<<<BATCH * NHEAD, 256, 0, stream>>>(qkv, amask, ao);
        gemm_bf16<3, false><<<g512, 256, 0, stream>>>(
            ao, wo + wD2, obias + oD, x, x, NTOK, DMODEL, DMODEL);
        ln_kernel<true><<<NTOK / 4, 256, 0, stream>>>(x, ln2w + oD, ln2b + oD, hbuf, NTOK);
        gemm_bf16<2, true><<<g2048, 256, 0, stream>>>(
            hbuf, wf1 + wDF, f1b + oF, nullptr, ff, NTOK, DFF, DMODEL);
        gemm_bf16<3, false><<<g512, 256, 0, stream>>>(
            ff, wf2 + wDF, f2b + oD, x, x, NTOK, DMODEL, DFF);
    }

    float* outf = (float*)d_out;
    ln_kernel<false><<<NTOK / 4, 256, 0, stream>>>(x, lnfw, lnfb, outf, NTOK);
    pool_kernel<<<BATCH, 64, 0, stream>>>(ids, outf, outf + (size_t)NTOK * DMODEL);
}